// Round 11
// baseline (82.417 us; speedup 1.0000x reference)
//
#include <hip/hip_runtime.h>
#include <math.h>

// ArcFace fused loss, B=512, C=100000, float32.
// loss_b = logsumexp_c(64*arcrow) - 64*theta_valid ; out = mean_b loss_b
// WAVE-SPECIALIZED single kernel (static split -> deterministic):
//   waves 0..3  (256 thr): early-exit NT scan of one-hot y (HBM stream).
//   waves 4..15 (768 thr): full exp2-sum over x (L3-resident stream).
// The two memory sources are driven CONCURRENTLY per CU instead of serially
// per block (round-8 structure left L3 idle in phase A and HBM idle in B;
// merging them per-iteration (r10) throttled issue rate -- this decouples via
// wave specialization instead). Finder thread loads the label logit scalar,
// latency hidden under the sum waves. Expected y traffic ~52%.
// Mean via one device-scope atomicAdd per block; d_out zeroed by a captured
// hipMemsetAsync node (no cross-replay carry).

#define BB 512
#define CC 100000
#define C4 (CC / 4)            // 25000 float4 per row
#define BLK 1024
#define NSCAN 256              // 4 scan waves
#define NSUM (BLK - NSCAN)     // 768 sum threads

// 64 * log2(e), for exp(64x-64) = exp2(K*x - K)
#define K64 92.33248261689366f

typedef unsigned int u32x4 __attribute__((ext_vector_type(4)));
typedef float f32x4 __attribute__((ext_vector_type(4)));

__device__ __forceinline__ float wave_reduce_add(float v) {
    #pragma unroll
    for (int off = 32; off > 0; off >>= 1)
        v += __shfl_down(v, off, 64);
    return v;
}

__device__ __forceinline__ float e64(float x) {
    return __builtin_amdgcn_exp2f(fmaf(K64, x, -K64));   // v_exp_f32
}

__global__ __launch_bounds__(BLK) void arcface_rows(const float* __restrict__ y_true,
                                                    const float* __restrict__ logits,
                                                    float* __restrict__ out) {
    const int row = blockIdx.x;
    const int tid = threadIdx.x;
    const u32x4* __restrict__ y4 = (const u32x4*)(y_true + (size_t)row * CC);
    const f32x4* __restrict__ x4 = (const f32x4*)(logits + (size_t)row * CC);

    __shared__ int s_found;
    __shared__ float s_val;
    __shared__ float s_sum[BLK / 64];

    if (tid == 0) s_found = 0;
    __syncthreads();
    volatile int* vfound = &s_found;

    float s0 = 0.0f, s1 = 0.0f;

    if (tid < NSCAN) {
        // ---- scan waves: early-exit one-hot scan (NT keeps y out of L3) ----
        #pragma unroll 1
        for (int i = tid; i < C4; i += NSCAN) {
            if (*vfound) break;            // poll first (round-8 order: best)
            const u32x4 u = __builtin_nontemporal_load(&y4[i]);
            if (u.x | u.y | u.z | u.w) {   // exactly one finder per row
                const int off = u.x ? 0 : (u.y ? 1 : (u.z ? 2 : 3));
                s_val = logits[(size_t)row * CC + 4 * i + off];
                *vfound = 1;
            }
        }
    } else {
        // ---- sum waves: full exp2-sum over x (L3-served stream) ----
        #pragma unroll 1
        for (int i = tid - NSCAN; i < C4; i += NSUM) {
            const f32x4 x = x4[i];
            s0 += e64(x.x); s1 += e64(x.y); s0 += e64(x.z); s1 += e64(x.w);
        }
    }

    float s = wave_reduce_add(s0 + s1);    // scan waves contribute 0
    if ((tid & 63) == 0) s_sum[tid >> 6] = s;
    __syncthreads();                       // also publishes s_val

    if (tid == 0) {
        float total = 0.0f;
        #pragma unroll
        for (int w = 0; w < BLK / 64; ++w) total += s_sum[w];

        const float val = s_val;
        // margin1=1, margin2=0.5, margin3=0
        const float THRESH = -0.8775825618903728f;  // cos(pi - 0.5)
        const float theta = cosf(acosf(val) + 0.5f);
        const float tv = (val > THRESH) ? theta : (-2.0f - theta);

        // swap label term: remove exp(64v-64), add exp(64*tv-64)
        total += e64(tv) - e64(val);

        // loss_b = (64 + log(total)) - 64*tv ; contribute loss_b/B to the mean
        const float loss = 64.0f + logf(total) - 64.0f * tv;
        atomicAdd(out, loss * (1.0f / (float)BB));   // device-scope by default
    }
}

extern "C" void kernel_launch(void* const* d_in, const int* in_sizes, int n_in,
                              void* d_out, int out_size, void* d_ws, size_t ws_size,
                              hipStream_t stream) {
    const float* y_true = (const float*)d_in[0];
    const float* logits = (const float*)d_in[1];
    float* out = (float*)d_out;

    hipMemsetAsync(out, 0, sizeof(float), stream);   // graph memset node
    arcface_rows<<<BB, BLK, 0, stream>>>(y_true, logits, out);
}

// Round 12
// 51.462 us; speedup vs baseline: 1.6015x; 1.6015x over previous
//
#include <hip/hip_runtime.h>
#include <math.h>

// ArcFace fused loss, B=512, C=100000, float32.
// loss_b = logsumexp_c(64*arcrow) - 64*theta_valid ; out = mean_b loss_b
// BLOCK-SPECIALIZED: 1024 blocks, even = SUM block (pure x exp2-sum, L3
// stream, round-8 phase-B loop shape), odd = SCAN block (early-exit NT y
// scan, HBM stream, round-8 phase-A loop shape). The two streams run on
// DIFFERENT CUs concurrently -- no intra-block coupling (r10/r11 both lost).
// Scan blocks write (corr, tv); sum blocks write total; tiny kernel2 combines
// loss_b = 64 + log(total+corr) - 64*tv and means. Disjoint plain stores,
// cross-kernel boundary flushes caches -> no coherence hazards, deterministic.

#define BB 512
#define CC 100000
#define C4 (CC / 4)            // 25000 float4 per row
#define BLK 1024

// 64 * log2(e), for exp(64x-64) = exp2(K*x - K)
#define K64 92.33248261689366f

typedef unsigned int u32x4 __attribute__((ext_vector_type(4)));
typedef float f32x4 __attribute__((ext_vector_type(4)));

__device__ __forceinline__ float wave_reduce_add(float v) {
    #pragma unroll
    for (int off = 32; off > 0; off >>= 1)
        v += __shfl_down(v, off, 64);
    return v;
}

__device__ __forceinline__ float e64(float x) {
    return __builtin_amdgcn_exp2f(fmaf(K64, x, -K64));   // v_exp_f32
}

__global__ __launch_bounds__(BLK) void arcface_main(const float* __restrict__ y_true,
                                                    const float* __restrict__ logits,
                                                    float* __restrict__ ws_total,
                                                    float* __restrict__ ws_corr,
                                                    float* __restrict__ ws_tv) {
    const int row = blockIdx.x >> 1;
    const int tid = threadIdx.x;

    if (blockIdx.x & 1) {
        // ---------------- SCAN block: early-exit one-hot scan of y ----------------
        const u32x4* __restrict__ y4 = (const u32x4*)(y_true + (size_t)row * CC);
        __shared__ int s_lab;
        if (tid == 0) s_lab = -1;
        __syncthreads();
        volatile int* vlab = &s_lab;

        #pragma unroll 1
        for (int i = tid; i < C4; i += BLK) {
            if (*vlab >= 0) break;             // poll-first (round-8 shape)
            const u32x4 u = __builtin_nontemporal_load(&y4[i]);
            if (u.x | u.y | u.z | u.w) {       // exactly one finder per row
                const int off = u.x ? 0 : (u.y ? 1 : (u.z ? 2 : 3));
                *vlab = 4 * i + off;
            }
        }
        __syncthreads();

        if (tid == 0) {
            const float val = logits[(size_t)row * CC + s_lab];
            // margin1=1, margin2=0.5, margin3=0
            const float THRESH = -0.8775825618903728f;  // cos(pi - 0.5)
            const float theta = cosf(acosf(val) + 0.5f);
            const float tv = (val > THRESH) ? theta : (-2.0f - theta);
            ws_corr[row] = e64(tv) - e64(val);  // swap label term in exp-sum
            ws_tv[row] = tv;
        }
    } else {
        // ---------------- SUM block: pure exp2-sum over x ----------------
        const f32x4* __restrict__ x4 = (const f32x4*)(logits + (size_t)row * CC);
        __shared__ float s_sum[BLK / 64];

        float s0 = 0.0f, s1 = 0.0f;
        #pragma unroll 1
        for (int i = tid; i < C4; i += BLK) {
            const f32x4 x = x4[i];
            s0 += e64(x.x); s1 += e64(x.y); s0 += e64(x.z); s1 += e64(x.w);
        }

        float s = wave_reduce_add(s0 + s1);
        if ((tid & 63) == 0) s_sum[tid >> 6] = s;
        __syncthreads();
        if (tid == 0) {
            float total = 0.0f;
            #pragma unroll
            for (int w = 0; w < BLK / 64; ++w) total += s_sum[w];
            ws_total[row] = total;
        }
    }
}

__global__ __launch_bounds__(BB) void combine_rows(const float* __restrict__ ws_total,
                                                   const float* __restrict__ ws_corr,
                                                   const float* __restrict__ ws_tv,
                                                   float* __restrict__ out) {
    const int tid = threadIdx.x;  // 512 threads = 512 rows
    const float tv = ws_tv[tid];
    float v = 64.0f + logf(ws_total[tid] + ws_corr[tid]) - 64.0f * tv;
    v = wave_reduce_add(v);
    __shared__ float s_wave[BB / 64];
    if ((tid & 63) == 0) s_wave[tid >> 6] = v;
    __syncthreads();
    if (tid == 0) {
        float t = 0.0f;
        #pragma unroll
        for (int w = 0; w < BB / 64; ++w) t += s_wave[w];
        out[0] = t * (1.0f / (float)BB);
    }
}

extern "C" void kernel_launch(void* const* d_in, const int* in_sizes, int n_in,
                              void* d_out, int out_size, void* d_ws, size_t ws_size,
                              hipStream_t stream) {
    const float* y_true = (const float*)d_in[0];
    const float* logits = (const float*)d_in[1];
    float* out = (float*)d_out;
    float* ws_total = (float*)d_ws;
    float* ws_corr = ws_total + BB;
    float* ws_tv = ws_corr + BB;

    arcface_main<<<2 * BB, BLK, 0, stream>>>(y_true, logits, ws_total, ws_corr, ws_tv);
    combine_rows<<<1, BB, 0, stream>>>(ws_total, ws_corr, ws_tv, out);
}